// Round 1
// baseline (1141.904 us; speedup 1.0000x reference)
//
#include <hip/hip_runtime.h>

#define N_NODES 100000
#define N_EDGES 3200000
#define F_IN    128
#define F_HID   32
#define F_OUT   3

// ---------------- degree / norm ----------------

__global__ void k_init_deg(float* __restrict__ deg) {
    int i = blockIdx.x * blockDim.x + threadIdx.x;
    if (i < N_NODES) deg[i] = 1.0f;  // self-loop contributes 1
}

__global__ void k_count(const int* __restrict__ col, float* __restrict__ deg) {
    int e = blockIdx.x * blockDim.x + threadIdx.x;
    if (e < N_EDGES) atomicAdd(&deg[col[e]], 1.0f);
}

__global__ void k_dinv(float* __restrict__ deg) {
    int i = blockIdx.x * blockDim.x + threadIdx.x;
    if (i < N_NODES) deg[i] = rsqrtf(deg[i]);  // deg >= 1 always
}

// ---------------- h1 = x @ W1 ; acc1 init = dinv^2 * h1 (self-loop) ----------------

__global__ void k_gemm1(const float* __restrict__ x, const float* __restrict__ W1,
                        const float* __restrict__ dinv,
                        float* __restrict__ h1, float* __restrict__ acc1) {
    __shared__ float Wlds[F_IN * F_HID];  // 16 KB, [k][f] row-major (matches W1 layout)
    int tid = threadIdx.x;
    for (int i = tid; i < F_IN * F_HID; i += 256) Wlds[i] = W1[i];
    __syncthreads();

    int gid = blockIdx.x * 256 + tid;          // gid = row*32 + f
    int row = gid >> 5;
    int f   = gid & 31;
    if (row >= N_NODES) return;

    const float4* x4 = (const float4*)(x + (size_t)row * F_IN);
    float acc = 0.0f;
#pragma unroll
    for (int k = 0; k < F_IN / 4; k++) {
        float4 xv = x4[k];  // broadcast across the 32 lanes sharing this row
        acc += xv.x * Wlds[(4 * k + 0) * F_HID + f];
        acc += xv.y * Wlds[(4 * k + 1) * F_HID + f];
        acc += xv.z * Wlds[(4 * k + 2) * F_HID + f];
        acc += xv.w * Wlds[(4 * k + 3) * F_HID + f];
    }
    h1[gid] = acc;
    float di = dinv[row];
    acc1[gid] = di * di * acc;  // self-loop term seeds the accumulator
}

// ---------------- conv1 scatter: acc1[c][f] += dinv[r]*dinv[c]*h1[r][f] ----------------

__global__ void k_scatter1(const int* __restrict__ row, const int* __restrict__ col,
                           const float* __restrict__ dinv, const float* __restrict__ h1,
                           float* __restrict__ acc1) {
    int gid = blockIdx.x * 256 + threadIdx.x;   // gid = e*32 + f   (max 102.4M < 2^31)
    int e = gid >> 5;
    int f = gid & 31;
    if (e >= N_EDGES) return;
    int r = row[e];
    int c = col[e];
    float nrm = dinv[r] * dinv[c];
    atomicAdd(&acc1[(size_t)c * F_HID + f], nrm * h1[(size_t)r * F_HID + f]);
}

// ---------------- hidden1 = tanh(acc1); h2 = hidden1 @ W2 ; out init = dinv^2*h2 ----------------

__global__ void k_act_gemm2(const float* __restrict__ acc1, const float* __restrict__ W2,
                            const float* __restrict__ dinv,
                            float* __restrict__ h2, float* __restrict__ out) {
    __shared__ float Wlds[F_HID * F_OUT];  // 96 floats, [k][j]
    int tid = threadIdx.x;
    if (tid < F_HID * F_OUT) Wlds[tid] = W2[tid];
    __syncthreads();

    int i = blockIdx.x * 256 + tid;  // one thread per node
    if (i >= N_NODES) return;

    const float4* a4 = (const float4*)(acc1 + (size_t)i * F_HID);
    float s0 = 0.0f, s1 = 0.0f, s2 = 0.0f;
#pragma unroll
    for (int k4 = 0; k4 < F_HID / 4; k4++) {
        float4 v = a4[k4];
        float t0 = tanhf(v.x), t1 = tanhf(v.y), t2 = tanhf(v.z), t3 = tanhf(v.w);
        int kb = 4 * k4;
        s0 += t0 * Wlds[(kb + 0) * 3 + 0] + t1 * Wlds[(kb + 1) * 3 + 0]
            + t2 * Wlds[(kb + 2) * 3 + 0] + t3 * Wlds[(kb + 3) * 3 + 0];
        s1 += t0 * Wlds[(kb + 0) * 3 + 1] + t1 * Wlds[(kb + 1) * 3 + 1]
            + t2 * Wlds[(kb + 2) * 3 + 1] + t3 * Wlds[(kb + 3) * 3 + 1];
        s2 += t0 * Wlds[(kb + 0) * 3 + 2] + t1 * Wlds[(kb + 1) * 3 + 2]
            + t2 * Wlds[(kb + 2) * 3 + 2] + t3 * Wlds[(kb + 3) * 3 + 2];
    }
    h2[(size_t)i * 3 + 0] = s0;
    h2[(size_t)i * 3 + 1] = s1;
    h2[(size_t)i * 3 + 2] = s2;
    float di = dinv[i];
    float d2 = di * di;
    out[(size_t)i * 3 + 0] = d2 * s0;  // self-loop seed; scatter2 adds on top
    out[(size_t)i * 3 + 1] = d2 * s1;
    out[(size_t)i * 3 + 2] = d2 * s2;
}

// ---------------- conv2 scatter: out[c][j] += dinv[r]*dinv[c]*h2[r][j] ----------------

__global__ void k_scatter2(const int* __restrict__ row, const int* __restrict__ col,
                           const float* __restrict__ dinv, const float* __restrict__ h2,
                           float* __restrict__ out) {
    int e = blockIdx.x * 256 + threadIdx.x;
    if (e >= N_EDGES) return;
    int r = row[e];
    int c = col[e];
    float nrm = dinv[r] * dinv[c];
    atomicAdd(&out[(size_t)c * 3 + 0], nrm * h2[(size_t)r * 3 + 0]);
    atomicAdd(&out[(size_t)c * 3 + 1], nrm * h2[(size_t)r * 3 + 1]);
    atomicAdd(&out[(size_t)c * 3 + 2], nrm * h2[(size_t)r * 3 + 2]);
}

// ---------------- launch ----------------

extern "C" void kernel_launch(void* const* d_in, const int* in_sizes, int n_in,
                              void* d_out, int out_size, void* d_ws, size_t ws_size,
                              hipStream_t stream) {
    const float* x   = (const float*)d_in[0];
    const int*   ei  = (const int*)d_in[1];      // [2, E] int32 per harness contract
    const float* W1  = (const float*)d_in[2];
    const float* W2  = (const float*)d_in[3];
    float*       out = (float*)d_out;

    const int* row = ei;
    const int* col = ei + N_EDGES;

    float* ws   = (float*)d_ws;
    float* dinv = ws;                                 // N
    float* h1   = ws + N_NODES;                       // 32N
    float* acc1 = ws + N_NODES + 32 * N_NODES;        // 32N
    float* h2   = ws + N_NODES + 64 * N_NODES;        // 3N

    const int B = 256;
    hipLaunchKernelGGL(k_init_deg, dim3((N_NODES + B - 1) / B), dim3(B), 0, stream, dinv);
    hipLaunchKernelGGL(k_count,    dim3((N_EDGES + B - 1) / B), dim3(B), 0, stream, col, dinv);
    hipLaunchKernelGGL(k_dinv,     dim3((N_NODES + B - 1) / B), dim3(B), 0, stream, dinv);
    hipLaunchKernelGGL(k_gemm1,    dim3((N_NODES * F_HID + B - 1) / B), dim3(B), 0, stream,
                       x, W1, dinv, h1, acc1);
    hipLaunchKernelGGL(k_scatter1, dim3((N_EDGES * 32 + B - 1) / B), dim3(B), 0, stream,
                       row, col, dinv, h1, acc1);
    hipLaunchKernelGGL(k_act_gemm2, dim3((N_NODES + B - 1) / B), dim3(B), 0, stream,
                       acc1, W2, dinv, h2, out);
    hipLaunchKernelGGL(k_scatter2, dim3((N_EDGES + B - 1) / B), dim3(B), 0, stream,
                       row, col, dinv, h2, out);
}

// Round 2
// 828.079 us; speedup vs baseline: 1.3790x; 1.3790x over previous
//
#include <hip/hip_runtime.h>

#define N_NODES 100000
#define N_EDGES 3200000
#define F_IN    128
#define F_HID   32
#define F_OUT   3

// ---------------- CSR build ----------------

__global__ __launch_bounds__(256) void k_zero(int* __restrict__ cnt) {
    int i = blockIdx.x * 256 + threadIdx.x;
    if (i < N_NODES) cnt[i] = 0;
}

__global__ __launch_bounds__(256) void k_hist(const int* __restrict__ col, int* __restrict__ cnt) {
    int e = blockIdx.x * 256 + threadIdx.x;
    if (e < N_EDGES) atomicAdd(&cnt[col[e]], 1);
}

// Single-block exclusive scan of cnt[0..N) -> off[i]; also seeds cursor (cnt[i] = off[i])
// and computes dinv[i] = rsqrt(deg+1). Hierarchical: wave shfl-scan + per-wave totals in LDS.
__global__ __launch_bounds__(1024) void k_scan(int* __restrict__ cnt, int* __restrict__ off,
                                               float* __restrict__ dinv) {
    __shared__ int ldsW[16];
    int tid  = threadIdx.x;
    int lane = tid & 63;
    int wid  = tid >> 6;
    int carry = 0;
    for (int base = 0; base < N_NODES; base += 1024) {
        int i = base + tid;
        int v = (i < N_NODES) ? cnt[i] : 0;
        // wave-inclusive scan
        int incl = v;
        #pragma unroll
        for (int s = 1; s < 64; s <<= 1) {
            int t = __shfl_up(incl, s);
            if (lane >= s) incl += t;
        }
        if (lane == 63) ldsW[wid] = incl;
        __syncthreads();
        if (wid == 0 && lane < 16) {
            int w = ldsW[lane];
            #pragma unroll
            for (int s = 1; s < 16; s <<= 1) {
                int t = __shfl_up(w, s);
                if (lane >= s) w += t;
            }
            ldsW[lane] = w;  // inclusive wave prefix
        }
        __syncthreads();
        int waveoff = (wid == 0) ? 0 : ldsW[wid - 1];
        int excl = carry + waveoff + (incl - v);
        if (i < N_NODES) {
            off[i]  = excl;
            cnt[i]  = excl;                    // cursor init for fill
            dinv[i] = rsqrtf((float)(v + 1));  // +1 self-loop
        }
        int tot = ldsW[15];
        __syncthreads();
        carry += tot;
    }
}

__global__ __launch_bounds__(256) void k_fill(const int* __restrict__ row, const int* __restrict__ col,
                                              int* __restrict__ cur, int* __restrict__ srt) {
    int e = blockIdx.x * 256 + threadIdx.x;
    if (e >= N_EDGES) return;
    int c = col[e];
    int p = atomicAdd(&cur[c], 1);
    srt[p] = row[e];
}
// after k_fill: cur[c] == end of node c's segment, off[c] == start.

// ---------------- h1 = x @ W1 ----------------

__global__ __launch_bounds__(256) void k_gemm1(const float* __restrict__ x, const float* __restrict__ W1,
                                               float* __restrict__ h1) {
    __shared__ float Wlds[F_IN * F_HID];  // 16 KB, [k][f]
    int tid = threadIdx.x;
    for (int i = tid; i < F_IN * F_HID; i += 256) Wlds[i] = W1[i];
    __syncthreads();

    int gid = blockIdx.x * 256 + tid;  // gid = row*32 + f
    int r   = gid >> 5;
    int f   = gid & 31;
    if (r >= N_NODES) return;

    const float4* x4 = (const float4*)(x + (size_t)r * F_IN);
    float acc = 0.0f;
#pragma unroll
    for (int k = 0; k < F_IN / 4; k++) {
        float4 xv = x4[k];  // broadcast across 32 lanes sharing this row
        acc += xv.x * Wlds[(4 * k + 0) * F_HID + f];
        acc += xv.y * Wlds[(4 * k + 1) * F_HID + f];
        acc += xv.z * Wlds[(4 * k + 2) * F_HID + f];
        acc += xv.w * Wlds[(4 * k + 3) * F_HID + f];
    }
    h1[gid] = acc;
}

// ---------------- conv1 gather + tanh + @W2, fused: h2[c] = tanh(Â h1)[c] @ W2 ----------------
// one wave per node; lane = half*32 + f; 2 neighbors per iteration

__global__ __launch_bounds__(256) void k_conv1(const int* __restrict__ off, const int* __restrict__ cur,
                                               const int* __restrict__ srt, const float* __restrict__ dinv,
                                               const float* __restrict__ h1, const float* __restrict__ W2,
                                               float* __restrict__ h2) {
    int wid  = threadIdx.x >> 6;
    int lane = threadIdx.x & 63;
    int c = blockIdx.x * 4 + wid;
    if (c >= N_NODES) return;
    int f    = lane & 31;
    int half = lane >> 5;

    int b = off[c], e = cur[c];
    float acc = 0.0f;
    for (int p = b + half; p < e; p += 2) {
        int r = srt[p];                               // broadcast within half-wave
        acc += dinv[r] * h1[(size_t)r * F_HID + f];   // coalesced 128B row
    }
    acc += __shfl_xor(acc, 32);  // combine halves; both halves now hold full sum

    float di  = dinv[c];
    float hid = tanhf(di * acc + di * di * h1[(size_t)c * F_HID + f]);

    float p0 = hid * W2[f * 3 + 0];
    float p1 = hid * W2[f * 3 + 1];
    float p2 = hid * W2[f * 3 + 2];
#pragma unroll
    for (int m = 16; m >= 1; m >>= 1) {  // reduce over f within each 32-half
        p0 += __shfl_xor(p0, m);
        p1 += __shfl_xor(p1, m);
        p2 += __shfl_xor(p2, m);
    }
    if (lane == 0) {
        h2[(size_t)c * 3 + 0] = p0;
        h2[(size_t)c * 3 + 1] = p1;
        h2[(size_t)c * 3 + 2] = p2;
    }
}

// ---------------- conv2 gather: out[c] = dinv[c]*(sum_nb dinv[r]*h2[r]) + dinv[c]^2*h2[c] ----------------
// one wave per node; lane = nb*4 + j; 16 neighbors per iteration

__global__ __launch_bounds__(256) void k_conv2(const int* __restrict__ off, const int* __restrict__ cur,
                                               const int* __restrict__ srt, const float* __restrict__ dinv,
                                               const float* __restrict__ h2, float* __restrict__ out) {
    int wid  = threadIdx.x >> 6;
    int lane = threadIdx.x & 63;
    int c = blockIdx.x * 4 + wid;
    if (c >= N_NODES) return;
    int nb = lane >> 2;
    int j  = lane & 3;

    int b = off[c], e = cur[c];
    float acc = 0.0f;
    for (int p = b + nb; p < e; p += 16) {
        int r = srt[p];
        if (j < 3) acc += dinv[r] * h2[(size_t)r * 3 + j];
    }
#pragma unroll
    for (int m = 32; m >= 4; m >>= 1) acc += __shfl_xor(acc, m);  // reduce over nb, keep j

    float di = dinv[c];
    if (lane < 3) out[(size_t)c * 3 + lane] = di * acc + di * di * h2[(size_t)c * 3 + lane];
}

// ---------------- launch ----------------

extern "C" void kernel_launch(void* const* d_in, const int* in_sizes, int n_in,
                              void* d_out, int out_size, void* d_ws, size_t ws_size,
                              hipStream_t stream) {
    const float* x   = (const float*)d_in[0];
    const int*   ei  = (const int*)d_in[1];  // [2, E] int32
    const float* W1  = (const float*)d_in[2];
    const float* W2  = (const float*)d_in[3];
    float*       out = (float*)d_out;

    const int* row = ei;
    const int* col = ei + N_EDGES;

    // workspace layout (floats/ints, 4B units). Total ~28.0 MB.
    char* ws = (char*)d_ws;
    int*   cnt  = (int*)ws;                          // N   (histogram, then cursor; cur==cnt)
    int*   off  = (int*)(ws + 4ull * N_NODES);       // N   (segment starts)
    float* dinv = (float*)(ws + 8ull * N_NODES);     // N
    int*   srt  = (int*)(ws + 12ull * N_NODES);      // E   (rows sorted by col)
    float* h1   = (float*)(ws + 12ull * N_NODES + 4ull * N_EDGES);                    // 32N
    float* h2   = (float*)(ws + 12ull * N_NODES + 4ull * N_EDGES + 128ull * N_NODES); // 3N

    const int B = 256;
    hipLaunchKernelGGL(k_zero, dim3((N_NODES + B - 1) / B), dim3(B), 0, stream, cnt);
    hipLaunchKernelGGL(k_hist, dim3((N_EDGES + B - 1) / B), dim3(B), 0, stream, col, cnt);
    hipLaunchKernelGGL(k_scan, dim3(1), dim3(1024), 0, stream, cnt, off, dinv);
    hipLaunchKernelGGL(k_fill, dim3((N_EDGES + B - 1) / B), dim3(B), 0, stream, row, col, cnt, srt);
    hipLaunchKernelGGL(k_gemm1, dim3((N_NODES * F_HID + B - 1) / B), dim3(B), 0, stream, x, W1, h1);
    hipLaunchKernelGGL(k_conv1, dim3((N_NODES + 3) / 4), dim3(B), 0, stream,
                       off, cnt, srt, dinv, h1, W2, h2);
    hipLaunchKernelGGL(k_conv2, dim3((N_NODES + 3) / 4), dim3(B), 0, stream,
                       off, cnt, srt, dinv, h2, out);
}

// Round 3
// 442.725 us; speedup vs baseline: 2.5793x; 1.8704x over previous
//
#include <hip/hip_runtime.h>

#define N_NODES 100000
#define N_EDGES 3200000
#define F_IN    128
#define F_HID   32
#define F_OUT   3

#define BSHIFT  8
#define BKSZ    256                               // nodes per bucket
#define NBKT    ((N_NODES + BKSZ - 1) / BKSZ)     // 391
#define CHUNK   4096                              // edges per block in hist/partition
#define NBLK_E  ((N_EDGES + CHUNK - 1) / CHUNK)   // 782
#define RBITS   17                                // row id fits in 17 bits (100000 < 2^17)
#define RMASK   0x1FFFF

// ---------------- CSR build: two-level counting sort, LDS-local atomics ----------------

__global__ __launch_bounds__(256) void k_zerob(int* __restrict__ bcnt) {
    int t = threadIdx.x;
    for (int i = t; i < NBKT; i += 256) bcnt[i] = 0;
}

__global__ __launch_bounds__(256) void k_bhist(const int* __restrict__ col, int* __restrict__ bcnt) {
    __shared__ int hist[NBKT];
    int t = threadIdx.x;
    for (int i = t; i < NBKT; i += 256) hist[i] = 0;
    __syncthreads();
    int e0 = blockIdx.x * CHUNK;
    int n  = min(CHUNK, N_EDGES - e0);
    for (int i = t; i < n; i += 256) atomicAdd(&hist[col[e0 + i] >> BSHIFT], 1);
    __syncthreads();
    for (int i = t; i < NBKT; i += 256) {
        int h = hist[i];
        if (h) atomicAdd(&bcnt[i], h);
    }
}

// one wave scans NBKT bucket totals -> bbase (exclusive), seeds gcur
__global__ __launch_bounds__(64) void k_bscan(const int* __restrict__ bcnt,
                                              int* __restrict__ bbase, int* __restrict__ gcur) {
    int lane = threadIdx.x;
    int carry = 0;
    for (int base = 0; base < NBKT; base += 64) {
        int i = base + lane;
        int v = (i < NBKT) ? bcnt[i] : 0;
        int incl = v;
        #pragma unroll
        for (int s = 1; s < 64; s <<= 1) {
            int u = __shfl_up(incl, s);
            if (lane >= s) incl += u;
        }
        if (i < NBKT) {
            int ex = carry + incl - v;
            bbase[i] = ex;
            gcur[i]  = ex;
        }
        carry += __shfl(incl, 63);
    }
    if (lane == 0) bbase[NBKT] = N_EDGES;
}

// partition edges into bucket regions; packed word = r | ((c & 255) << 17)
__global__ __launch_bounds__(256) void k_part(const int* __restrict__ row, const int* __restrict__ col,
                                              int* __restrict__ gcur, unsigned* __restrict__ bkt) {
    __shared__ int hist[NBKT];
    __shared__ int base[NBKT];
    int t = threadIdx.x;
    for (int i = t; i < NBKT; i += 256) hist[i] = 0;
    __syncthreads();

    int e0 = blockIdx.x * CHUNK;
    int n  = min(CHUNK, N_EDGES - e0);
    int r[16], c[16];
#pragma unroll
    for (int k = 0; k < 16; k++) {
        int idx = t + k * 256;
        if (idx < n) {
            r[k] = row[e0 + idx];
            c[k] = col[e0 + idx];
            atomicAdd(&hist[c[k] >> BSHIFT], 1);
        }
    }
    __syncthreads();
    for (int i = t; i < NBKT; i += 256) {
        int h = hist[i];
        base[i] = h ? atomicAdd(&gcur[i], h) : 0;
    }
    __syncthreads();
    for (int i = t; i < NBKT; i += 256) hist[i] = 0;
    __syncthreads();
#pragma unroll
    for (int k = 0; k < 16; k++) {
        int idx = t + k * 256;
        if (idx < n) {
            int b = c[k] >> BSHIFT;
            int p = base[b] + atomicAdd(&hist[b], 1);
            bkt[p] = (unsigned)r[k] | ((unsigned)(c[k] & (BKSZ - 1)) << RBITS);
        }
    }
}

// per-bucket fine sort: LDS hist + scan + LDS-cursor scatter; emits off[], dinv[], srt[]
__global__ __launch_bounds__(256) void k_bucket(const unsigned* __restrict__ bkt,
                                                const int* __restrict__ bbase,
                                                int* __restrict__ off, float* __restrict__ dinv,
                                                int* __restrict__ srt) {
    __shared__ int cnt[BKSZ];
    __shared__ int cur[BKSZ];
    __shared__ int wtot[4];
    int t = threadIdx.x, b = blockIdx.x;
    int s = bbase[b], e = bbase[b + 1], m = e - s;
    cnt[t] = 0;
    __syncthreads();
    for (int i = t; i < m; i += 256) atomicAdd(&cnt[bkt[s + i] >> RBITS], 1);
    __syncthreads();

    int v = cnt[t];
    int lane = t & 63, wid = t >> 6;
    int incl = v;
    #pragma unroll
    for (int sft = 1; sft < 64; sft <<= 1) {
        int u = __shfl_up(incl, sft);
        if (lane >= sft) incl += u;
    }
    if (lane == 63) wtot[wid] = incl;
    __syncthreads();
    int wpre = 0;
    for (int w = 0; w < wid; w++) wpre += wtot[w];
    int excl = wpre + incl - v;
    cur[t] = s + excl;

    int g = (b << BSHIFT) + t;
    if (g < N_NODES) {
        off[g]  = s + excl;
        dinv[g] = rsqrtf((float)(v + 1));  // +1 self-loop
    }
    if (b == 0 && t == 0) off[N_NODES] = N_EDGES;
    __syncthreads();
    for (int i = t; i < m; i += 256) {
        unsigned x = bkt[s + i];
        int p = atomicAdd(&cur[x >> RBITS], 1);
        srt[p] = (int)(x & RMASK);
    }
}

// ---------------- h1 = x @ W1 ----------------

__global__ __launch_bounds__(256) void k_gemm1(const float* __restrict__ x, const float* __restrict__ W1,
                                               float* __restrict__ h1) {
    __shared__ float Wlds[F_IN * F_HID];  // 16 KB, [k][f]
    int tid = threadIdx.x;
    for (int i = tid; i < F_IN * F_HID; i += 256) Wlds[i] = W1[i];
    __syncthreads();

    int gid = blockIdx.x * 256 + tid;  // gid = row*32 + f
    int r   = gid >> 5;
    int f   = gid & 31;
    if (r >= N_NODES) return;

    const float4* x4 = (const float4*)(x + (size_t)r * F_IN);
    float acc = 0.0f;
#pragma unroll
    for (int k = 0; k < F_IN / 4; k++) {
        float4 xv = x4[k];
        acc += xv.x * Wlds[(4 * k + 0) * F_HID + f];
        acc += xv.y * Wlds[(4 * k + 1) * F_HID + f];
        acc += xv.z * Wlds[(4 * k + 2) * F_HID + f];
        acc += xv.w * Wlds[(4 * k + 3) * F_HID + f];
    }
    h1[gid] = acc;
}

// ---------------- conv1 gather + tanh + @W2 fused ----------------

__global__ __launch_bounds__(256) void k_conv1(const int* __restrict__ off,
                                               const int* __restrict__ srt, const float* __restrict__ dinv,
                                               const float* __restrict__ h1, const float* __restrict__ W2,
                                               float* __restrict__ h2) {
    int wid  = threadIdx.x >> 6;
    int lane = threadIdx.x & 63;
    int c = blockIdx.x * 4 + wid;
    if (c >= N_NODES) return;
    int f    = lane & 31;
    int half = lane >> 5;

    int b = off[c], e = off[c + 1];
    float acc = 0.0f;
    for (int p = b + half; p < e; p += 2) {
        int r = srt[p];
        acc += dinv[r] * h1[(size_t)r * F_HID + f];
    }
    acc += __shfl_xor(acc, 32);

    float di  = dinv[c];
    float hid = tanhf(di * acc + di * di * h1[(size_t)c * F_HID + f]);

    float p0 = hid * W2[f * 3 + 0];
    float p1 = hid * W2[f * 3 + 1];
    float p2 = hid * W2[f * 3 + 2];
#pragma unroll
    for (int m = 16; m >= 1; m >>= 1) {
        p0 += __shfl_xor(p0, m);
        p1 += __shfl_xor(p1, m);
        p2 += __shfl_xor(p2, m);
    }
    if (lane == 0) {
        h2[(size_t)c * 3 + 0] = p0;
        h2[(size_t)c * 3 + 1] = p1;
        h2[(size_t)c * 3 + 2] = p2;
    }
}

// ---------------- conv2 gather ----------------

__global__ __launch_bounds__(256) void k_conv2(const int* __restrict__ off,
                                               const int* __restrict__ srt, const float* __restrict__ dinv,
                                               const float* __restrict__ h2, float* __restrict__ out) {
    int wid  = threadIdx.x >> 6;
    int lane = threadIdx.x & 63;
    int c = blockIdx.x * 4 + wid;
    if (c >= N_NODES) return;
    int nb = lane >> 2;
    int j  = lane & 3;

    int b = off[c], e = off[c + 1];
    float acc = 0.0f;
    for (int p = b + nb; p < e; p += 16) {
        int r = srt[p];
        if (j < 3) acc += dinv[r] * h2[(size_t)r * 3 + j];
    }
#pragma unroll
    for (int m = 32; m >= 4; m >>= 1) acc += __shfl_xor(acc, m);

    float di = dinv[c];
    if (lane < 3) out[(size_t)c * 3 + lane] = di * acc + di * di * h2[(size_t)c * 3 + lane];
}

// ---------------- launch ----------------

extern "C" void kernel_launch(void* const* d_in, const int* in_sizes, int n_in,
                              void* d_out, int out_size, void* d_ws, size_t ws_size,
                              hipStream_t stream) {
    const float* x   = (const float*)d_in[0];
    const int*   ei  = (const int*)d_in[1];  // [2, E] int32
    const float* W1  = (const float*)d_in[2];
    const float* W2  = (const float*)d_in[3];
    float*       out = (float*)d_out;

    const int* row = ei;
    const int* col = ei + N_EDGES;

    // workspace (bytes):
    //  [0)              bkt  : E u32 (12.8 MB)  -- dead after k_bucket, reused as h1 (32N f32 = same size)
    //  [12.8M)          srt  : E int (12.8 MB)
    //  [25.6M)          off  : N+1 int
    //  [+]              dinv : N float
    //  [+]              bcnt : NBKT, bbase : NBKT+1, gcur : NBKT
    //  [+]              h2   : 3N float
    // total ~27.6 MB (<= 28.0 MB proven in R2)
    char* ws = (char*)d_ws;
    unsigned* bkt = (unsigned*)ws;
    float*    h1  = (float*)ws;                                // alias of bkt (post-k_bucket)
    int*      srt = (int*)(ws + 4ull * N_EDGES);
    char*     p2  = ws + 8ull * N_EDGES;
    int*      off   = (int*)p2;                         p2 += 4ull * (N_NODES + 1);
    float*    dinv  = (float*)p2;                       p2 += 4ull * N_NODES;
    int*      bcnt  = (int*)p2;                         p2 += 4ull * NBKT;
    int*      bbase = (int*)p2;                         p2 += 4ull * (NBKT + 1);
    int*      gcur  = (int*)p2;                         p2 += 4ull * NBKT;
    float*    h2    = (float*)p2;

    const int B = 256;
    hipLaunchKernelGGL(k_zerob,  dim3(1),        dim3(B), 0, stream, bcnt);
    hipLaunchKernelGGL(k_bhist,  dim3(NBLK_E),   dim3(B), 0, stream, col, bcnt);
    hipLaunchKernelGGL(k_bscan,  dim3(1),        dim3(64), 0, stream, bcnt, bbase, gcur);
    hipLaunchKernelGGL(k_part,   dim3(NBLK_E),   dim3(B), 0, stream, row, col, gcur, bkt);
    hipLaunchKernelGGL(k_bucket, dim3(NBKT),     dim3(B), 0, stream, bkt, bbase, off, dinv, srt);
    hipLaunchKernelGGL(k_gemm1,  dim3((N_NODES * F_HID + B - 1) / B), dim3(B), 0, stream, x, W1, h1);
    hipLaunchKernelGGL(k_conv1,  dim3((N_NODES + 3) / 4), dim3(B), 0, stream,
                       off, srt, dinv, h1, W2, h2);
    hipLaunchKernelGGL(k_conv2,  dim3((N_NODES + 3) / 4), dim3(B), 0, stream,
                       off, srt, dinv, h2, out);
}